// Round 1
// baseline (7811.045 us; speedup 1.0000x reference)
//
#include <hip/hip_runtime.h>
#include <math.h>

typedef unsigned short u16;
typedef short short8 __attribute__((ext_vector_type(8)));
typedef float floatx4 __attribute__((ext_vector_type(4)));

__device__ __forceinline__ u16 f2bf(float f) {
  unsigned int u = __float_as_uint(f);
  u += 0x7fffu + ((u >> 16) & 1u);
  return (u16)(u >> 16);
}

// ---------------------------------------------------------------------------
// Transpose + f32->bf16 convert: W[K][N] -> Wt[N][K]
// ---------------------------------------------------------------------------
__global__ __launch_bounds__(256) void transpose_bf16(
    const float* __restrict__ W, u16* __restrict__ Wt, int K, int N)
{
  __shared__ float tile[32][33];
  int tx = threadIdx.x, ty = threadIdx.y;
  int n0 = blockIdx.x * 32, k0 = blockIdx.y * 32;
#pragma unroll
  for (int i = 0; i < 4; i++) {
    int k = k0 + ty + i * 8;
    tile[ty + i * 8][tx] = W[(size_t)k * N + n0 + tx];
  }
  __syncthreads();
#pragma unroll
  for (int i = 0; i < 4; i++) {
    int n = n0 + ty + i * 8;
    Wt[(size_t)n * K + k0 + tx] = f2bf(tile[tx][ty + i * 8]);
  }
}

// ---------------------------------------------------------------------------
// Embedding: x[bs][:] = tok_emb[X[bs]][:] + pos_emb[s][:]; also bf16 copy
// ---------------------------------------------------------------------------
__global__ __launch_bounds__(256) void embed_kernel(
    const int* __restrict__ X, const float* __restrict__ tok,
    const float* __restrict__ pos, float* __restrict__ x, u16* __restrict__ xbf)
{
  int bs = blockIdx.x, t = threadIdx.x;
  int id = X[bs];
  int s = bs & 1023;
  float4 tv = *(const float4*)(tok + (size_t)id * 1024 + t * 4);
  float4 pv = *(const float4*)(pos + (size_t)s * 1024 + t * 4);
  float4 o;
  o.x = tv.x + pv.x; o.y = tv.y + pv.y; o.z = tv.z + pv.z; o.w = tv.w + pv.w;
  *(float4*)(x + (size_t)bs * 1024 + t * 4) = o;
  ushort4 ob; ob.x = f2bf(o.x); ob.y = f2bf(o.y); ob.z = f2bf(o.z); ob.w = f2bf(o.w);
  *(ushort4*)(xbf + (size_t)bs * 1024 + t * 4) = ob;
}

// ---------------------------------------------------------------------------
// bf16 MFMA GEMM: C[M][N] = A[M][K] @ Bt[N][K]^T + bias
// A row-major bf16, Bt row-major bf16 (i.e. B pre-transposed).
// mode 0: C f32.  mode 1: C bf16 with exact GELU applied.
// 64x64 workgroup tile, 4 waves in 2x2, each wave 32x32 (2x2 of 16x16 MFMA).
// ---------------------------------------------------------------------------
__global__ __launch_bounds__(256) void gemm_bf16(
    const u16* __restrict__ A, const u16* __restrict__ Bt,
    const float* __restrict__ bias, void* __restrict__ Cout,
    int M, int N, int K, int mode)
{
  __shared__ alignas(16) u16 As[64][72];  // +8 pad: 144B row stride -> 2-way bank alias (free)
  __shared__ alignas(16) u16 Bs[64][72];

  int t = threadIdx.x;
  int row0 = blockIdx.y * 64, col0 = blockIdx.x * 64;
  int lane = t & 63, wv = t >> 6;
  int quad = lane >> 4, l16 = lane & 15;
  int wr = (wv >> 1) * 32, wc = (wv & 1) * 32;

  floatx4 acc[2][2];
#pragma unroll
  for (int i = 0; i < 2; i++)
#pragma unroll
    for (int j = 0; j < 2; j++) acc[i][j] = (floatx4){0.f, 0.f, 0.f, 0.f};

  // staging: 512 chunks of 8 bf16 per tile, 2 per thread
  int c0 = t, c1 = t + 256;
  int ar0 = c0 >> 3, ac0 = (c0 & 7) * 8;
  int ar1 = c1 >> 3, ac1 = (c1 & 7) * 8;

  for (int k0 = 0; k0 < K; k0 += 64) {
    *(short8*)&As[ar0][ac0] = *(const short8*)(A + (size_t)(row0 + ar0) * K + k0 + ac0);
    *(short8*)&As[ar1][ac1] = *(const short8*)(A + (size_t)(row0 + ar1) * K + k0 + ac1);
    *(short8*)&Bs[ar0][ac0] = *(const short8*)(Bt + (size_t)(col0 + ar0) * K + k0 + ac0);
    *(short8*)&Bs[ar1][ac1] = *(const short8*)(Bt + (size_t)(col0 + ar1) * K + k0 + ac1);
    __syncthreads();
#pragma unroll
    for (int ks = 0; ks < 64; ks += 32) {
      int kf = ks + quad * 8;
      short8 a0 = *(const short8*)&As[wr + l16][kf];
      short8 a1 = *(const short8*)&As[wr + 16 + l16][kf];
      short8 b0 = *(const short8*)&Bs[wc + l16][kf];
      short8 b1 = *(const short8*)&Bs[wc + 16 + l16][kf];
      acc[0][0] = __builtin_amdgcn_mfma_f32_16x16x32_bf16(a0, b0, acc[0][0], 0, 0, 0);
      acc[0][1] = __builtin_amdgcn_mfma_f32_16x16x32_bf16(a0, b1, acc[0][1], 0, 0, 0);
      acc[1][0] = __builtin_amdgcn_mfma_f32_16x16x32_bf16(a1, b0, acc[1][0], 0, 0, 0);
      acc[1][1] = __builtin_amdgcn_mfma_f32_16x16x32_bf16(a1, b1, acc[1][1], 0, 0, 0);
    }
    __syncthreads();
  }

#pragma unroll
  for (int ti = 0; ti < 2; ti++)
#pragma unroll
    for (int tj = 0; tj < 2; tj++) {
      int rbase = row0 + wr + ti * 16 + quad * 4;
      int c = col0 + wc + tj * 16 + l16;
      float bv = bias[c];
#pragma unroll
      for (int r = 0; r < 4; r++) {
        float v = acc[ti][tj][r] + bv;
        size_t idx = (size_t)(rbase + r) * N + c;
        if (mode == 0) {
          ((float*)Cout)[idx] = v;
        } else {
          float g = 0.5f * v * (1.f + erff(v * 0.70710678118f));
          ((u16*)Cout)[idx] = f2bf(g);
        }
      }
    }
}

// ---------------------------------------------------------------------------
// Attention: one block per (b,h,q). qkv f32 [B,S,H,3*HD] laid out as
// qkv[b][s][h*192 + {0:q,64:k,128:v} + d]. Exact causal softmax.
// Output bf16 [B,S,D] with D-index = h*64+d.
// ---------------------------------------------------------------------------
__global__ __launch_bounds__(256) void attn_kernel(
    const float* __restrict__ qkv, u16* __restrict__ attn_out)
{
  __shared__ float qv[64];
  __shared__ float sc[1024];
  __shared__ float red[256];
  __shared__ float po[4][64];

  int blk = blockIdx.x;
  int q = blk & 1023;
  int h = (blk >> 10) & 15;
  int b = blk >> 14;
  int t = threadIdx.x;

  const float* qptr = qkv + ((size_t)(b * 1024 + q) * 3072) + h * 192;
  if (t < 64) qv[t] = qptr[t];
  __syncthreads();

  float lmax = -1e30f;
  for (int j = t; j <= q; j += 256) {
    const float* kptr = qkv + ((size_t)(b * 1024 + j) * 3072) + h * 192 + 64;
    float s = 0.f;
#pragma unroll
    for (int d = 0; d < 64; d += 4) {
      float4 kk = *(const float4*)(kptr + d);
      s += qv[d] * kk.x + qv[d + 1] * kk.y + qv[d + 2] * kk.z + qv[d + 3] * kk.w;
    }
    s *= 0.125f;  // 1/sqrt(64)
    sc[j] = s;
    lmax = fmaxf(lmax, s);
  }
  red[t] = lmax; __syncthreads();
  for (int off = 128; off > 0; off >>= 1) {
    if (t < off) red[t] = fmaxf(red[t], red[t + off]);
    __syncthreads();
  }
  float mx = red[0];
  __syncthreads();

  float lsum = 0.f;
  for (int j = t; j <= q; j += 256) {
    float e = __expf(sc[j] - mx);
    sc[j] = e;
    lsum += e;
  }
  red[t] = lsum; __syncthreads();
  for (int off = 128; off > 0; off >>= 1) {
    if (t < off) red[t] += red[t + off];
    __syncthreads();
  }
  float inv = 1.f / red[0];
  __syncthreads();

  int d = t & 63, part = t >> 6;
  float pacc = 0.f;
  for (int j = part; j <= q; j += 4) {
    pacc += sc[j] * qkv[((size_t)(b * 1024 + j) * 3072) + h * 192 + 128 + d];
  }
  po[part][d] = pacc;
  __syncthreads();
  if (t < 64) {
    float o = (po[0][t] + po[1][t] + po[2][t] + po[3][t]) * inv;
    attn_out[((size_t)(b * 1024 + q) * 1024) + h * 64 + t] = f2bf(o);
  }
}

// ---------------------------------------------------------------------------
// LayerNorm( xin + add ) * sc + bi  -> xout (f32) and xbf (bf16). add may be null.
// One block per row of 1024.
// ---------------------------------------------------------------------------
__global__ __launch_bounds__(256) void ln_kernel(
    const float* __restrict__ xin, const float* __restrict__ add,
    const float* __restrict__ sc, const float* __restrict__ bi,
    float* __restrict__ xout, u16* __restrict__ xbf)
{
  int row = blockIdx.x, t = threadIdx.x;
  float4 v = *(const float4*)(xin + (size_t)row * 1024 + t * 4);
  if (add) {
    float4 a = *(const float4*)(add + (size_t)row * 1024 + t * 4);
    v.x += a.x; v.y += a.y; v.z += a.z; v.w += a.w;
  }
  float s1 = v.x + v.y + v.z + v.w;
  float s2 = v.x * v.x + v.y * v.y + v.z * v.z + v.w * v.w;
#pragma unroll
  for (int off = 32; off > 0; off >>= 1) {
    s1 += __shfl_down(s1, off);
    s2 += __shfl_down(s2, off);
  }
  __shared__ float r1[4], r2[4];
  int lane = t & 63, wv = t >> 6;
  if (lane == 0) { r1[wv] = s1; r2[wv] = s2; }
  __syncthreads();
  float S1 = r1[0] + r1[1] + r1[2] + r1[3];
  float S2 = r2[0] + r2[1] + r2[2] + r2[3];
  float m = S1 * (1.f / 1024.f);
  float var = S2 * (1.f / 1024.f) - m * m;
  float inv = rsqrtf(var + 1e-5f);
  float4 sv = *(const float4*)(sc + t * 4);
  float4 bv = *(const float4*)(bi + t * 4);
  float4 o;
  o.x = (v.x - m) * inv * sv.x + bv.x;
  o.y = (v.y - m) * inv * sv.y + bv.y;
  o.z = (v.z - m) * inv * sv.z + bv.z;
  o.w = (v.w - m) * inv * sv.w + bv.w;
  *(float4*)(xout + (size_t)row * 1024 + t * 4) = o;
  ushort4 ob; ob.x = f2bf(o.x); ob.y = f2bf(o.y); ob.z = f2bf(o.z); ob.w = f2bf(o.w);
  *(ushort4*)(xbf + (size_t)row * 1024 + t * 4) = ob;
}

// ---------------------------------------------------------------------------
// In-place row softmax over V=32000. One block per row.
// ---------------------------------------------------------------------------
__global__ __launch_bounds__(256) void softmax_kernel(float* __restrict__ out)
{
  __shared__ float red[256];
  int row = blockIdx.x, t = threadIdx.x;
  float* p = out + (size_t)row * 32000;
  float lmax = -1e30f;
  for (int j = t; j < 32000; j += 256) lmax = fmaxf(lmax, p[j]);
  red[t] = lmax; __syncthreads();
  for (int off = 128; off > 0; off >>= 1) {
    if (t < off) red[t] = fmaxf(red[t], red[t + off]);
    __syncthreads();
  }
  float mx = red[0];
  __syncthreads();
  float lsum = 0.f;
  for (int j = t; j < 32000; j += 256) {
    float e = __expf(p[j] - mx);
    p[j] = e;
    lsum += e;
  }
  red[t] = lsum; __syncthreads();
  for (int off = 128; off > 0; off >>= 1) {
    if (t < off) red[t] += red[t + off];
    __syncthreads();
  }
  float inv = 1.f / red[0];
  for (int j = t; j < 32000; j += 256) p[j] *= inv;
}

// ---------------------------------------------------------------------------
// Launch
// ---------------------------------------------------------------------------
extern "C" void kernel_launch(void* const* d_in, const int* in_sizes, int n_in,
                              void* d_out, int out_size, void* d_ws, size_t ws_size,
                              hipStream_t stream)
{
  const int*   X       = (const int*)d_in[0];
  const float* tok_emb = (const float*)d_in[1];
  const float* pos_emb = (const float*)d_in[2];
  const float* qkv_w   = (const float*)d_in[3];
  const float* qkv_b   = (const float*)d_in[4];
  const float* out_w   = (const float*)d_in[5];
  const float* out_b   = (const float*)d_in[6];
  const float* ln1_s   = (const float*)d_in[7];
  const float* ln1_b   = (const float*)d_in[8];
  const float* ln2_s   = (const float*)d_in[9];
  const float* ln2_b   = (const float*)d_in[10];
  const float* ff1_w   = (const float*)d_in[11];
  const float* ff1_b   = (const float*)d_in[12];
  const float* ff2_w   = (const float*)d_in[13];
  const float* ff2_b   = (const float*)d_in[14];
  const float* lnf_s   = (const float*)d_in[15];
  const float* lnf_b   = (const float*)d_in[16];
  const float* head_w  = (const float*)d_in[17];
  const float* head_b  = (const float*)d_in[18];

  char* ws = (char*)d_ws;
  float* x      = (float*)ws;            ws += 2048ull * 1024 * 4;
  u16*   xbf    = (u16*)ws;              ws += 2048ull * 1024 * 2;
  float* qkvbuf = (float*)ws;            ws += 2048ull * 3072 * 4;
  u16*   attnbf = (u16*)ws;              ws += 2048ull * 1024 * 2;
  float* tmp    = (float*)ws;            ws += 2048ull * 1024 * 4;
  u16*   hbf    = (u16*)ws;              ws += 2048ull * 4096 * 2;
  u16*   qkvT   = (u16*)ws;              ws += 3072ull * 1024 * 2;
  u16*   outT   = (u16*)ws;              ws += 1024ull * 1024 * 2;
  u16*   ff1T   = (u16*)ws;              ws += 4096ull * 1024 * 2;
  u16*   ff2T   = (u16*)ws;              ws += 1024ull * 4096 * 2;
  u16*   headT  = (u16*)ws;              ws += 32000ull * 1024 * 2;

  dim3 tb(32, 8);
  transpose_bf16<<<dim3(3072 / 32, 1024 / 32), tb, 0, stream>>>(qkv_w, qkvT, 1024, 3072);
  transpose_bf16<<<dim3(1024 / 32, 1024 / 32), tb, 0, stream>>>(out_w, outT, 1024, 1024);
  transpose_bf16<<<dim3(4096 / 32, 1024 / 32), tb, 0, stream>>>(ff1_w, ff1T, 1024, 4096);
  transpose_bf16<<<dim3(1024 / 32, 4096 / 32), tb, 0, stream>>>(ff2_w, ff2T, 4096, 1024);
  transpose_bf16<<<dim3(32000 / 32, 1024 / 32), tb, 0, stream>>>(head_w, headT, 1024, 32000);

  embed_kernel<<<2048, 256, 0, stream>>>(X, tok_emb, pos_emb, x, xbf);

  for (int l = 0; l < 6; l++) {
    gemm_bf16<<<dim3(3072 / 64, 2048 / 64), 256, 0, stream>>>(
        xbf, qkvT, qkv_b, qkvbuf, 2048, 3072, 1024, 0);
    attn_kernel<<<2 * 16 * 1024, 256, 0, stream>>>(qkvbuf, attnbf);
    gemm_bf16<<<dim3(1024 / 64, 2048 / 64), 256, 0, stream>>>(
        attnbf, outT, out_b, tmp, 2048, 1024, 1024, 0);
    ln_kernel<<<2048, 256, 0, stream>>>(x, tmp, ln1_s, ln1_b, x, xbf);
    gemm_bf16<<<dim3(4096 / 64, 2048 / 64), 256, 0, stream>>>(
        xbf, ff1T, ff1_b, hbf, 2048, 4096, 1024, 1);
    gemm_bf16<<<dim3(1024 / 64, 2048 / 64), 256, 0, stream>>>(
        hbf, ff2T, ff2_b, tmp, 2048, 1024, 4096, 0);
    ln_kernel<<<2048, 256, 0, stream>>>(x, tmp, ln2_s, ln2_b, x, xbf);
  }

  ln_kernel<<<2048, 256, 0, stream>>>(x, nullptr, lnf_s, lnf_b, x, xbf);
  gemm_bf16<<<dim3(32000 / 64, 2048 / 64), 256, 0, stream>>>(
      xbf, headT, head_b, (float*)d_out, 2048, 32000, 1024, 0);
  softmax_kernel<<<2048, 256, 0, stream>>>((float*)d_out);
}

// Round 2
// 2778.408 us; speedup vs baseline: 2.8113x; 2.8113x over previous
//
#include <hip/hip_runtime.h>
#include <math.h>

typedef unsigned short u16;
typedef short short8 __attribute__((ext_vector_type(8)));
typedef float floatx4 __attribute__((ext_vector_type(4)));

__device__ __forceinline__ u16 f2bf(float f) {
  unsigned int u = __float_as_uint(f);
  u += 0x7fffu + ((u >> 16) & 1u);
  return (u16)(u >> 16);
}

// ---------------------------------------------------------------------------
// Transpose + f32->bf16 convert: W[K][N] -> Wt[N][K]
// ---------------------------------------------------------------------------
__global__ __launch_bounds__(256) void transpose_bf16(
    const float* __restrict__ W, u16* __restrict__ Wt, int K, int N)
{
  __shared__ float tile[32][33];
  int tx = threadIdx.x, ty = threadIdx.y;
  int n0 = blockIdx.x * 32, k0 = blockIdx.y * 32;
#pragma unroll
  for (int i = 0; i < 4; i++) {
    int k = k0 + ty + i * 8;
    tile[ty + i * 8][tx] = W[(size_t)k * N + n0 + tx];
  }
  __syncthreads();
#pragma unroll
  for (int i = 0; i < 4; i++) {
    int n = n0 + ty + i * 8;
    Wt[(size_t)n * K + k0 + tx] = f2bf(tile[tx][ty + i * 8]);
  }
}

// ---------------------------------------------------------------------------
// Embedding: x[bs][:] = tok_emb[X[bs]][:] + pos_emb[s][:]; also bf16 copy
// ---------------------------------------------------------------------------
__global__ __launch_bounds__(256) void embed_kernel(
    const int* __restrict__ X, const float* __restrict__ tok,
    const float* __restrict__ pos, float* __restrict__ x, u16* __restrict__ xbf)
{
  int bs = blockIdx.x, t = threadIdx.x;
  int id = X[bs];
  int s = bs & 1023;
  float4 tv = *(const float4*)(tok + (size_t)id * 1024 + t * 4);
  float4 pv = *(const float4*)(pos + (size_t)s * 1024 + t * 4);
  float4 o;
  o.x = tv.x + pv.x; o.y = tv.y + pv.y; o.z = tv.z + pv.z; o.w = tv.w + pv.w;
  *(float4*)(x + (size_t)bs * 1024 + t * 4) = o;
  ushort4 ob; ob.x = f2bf(o.x); ob.y = f2bf(o.y); ob.z = f2bf(o.z); ob.w = f2bf(o.w);
  *(ushort4*)(xbf + (size_t)bs * 1024 + t * 4) = ob;
}

// ---------------------------------------------------------------------------
// bf16 MFMA GEMM: C[M][N] = A[M][K] @ Bt[N][K]^T + bias
// mode 0: C f32.  mode 1: C bf16 with exact GELU applied.
// ---------------------------------------------------------------------------
__global__ __launch_bounds__(256) void gemm_bf16(
    const u16* __restrict__ A, const u16* __restrict__ Bt,
    const float* __restrict__ bias, void* __restrict__ Cout,
    int M, int N, int K, int mode)
{
  __shared__ alignas(16) u16 As[64][72];
  __shared__ alignas(16) u16 Bs[64][72];

  int t = threadIdx.x;
  int row0 = blockIdx.y * 64, col0 = blockIdx.x * 64;
  int lane = t & 63, wv = t >> 6;
  int quad = lane >> 4, l16 = lane & 15;
  int wr = (wv >> 1) * 32, wc = (wv & 1) * 32;

  floatx4 acc[2][2];
#pragma unroll
  for (int i = 0; i < 2; i++)
#pragma unroll
    for (int j = 0; j < 2; j++) acc[i][j] = (floatx4){0.f, 0.f, 0.f, 0.f};

  int c0 = t, c1 = t + 256;
  int ar0 = c0 >> 3, ac0 = (c0 & 7) * 8;
  int ar1 = c1 >> 3, ac1 = (c1 & 7) * 8;

  for (int k0 = 0; k0 < K; k0 += 64) {
    *(short8*)&As[ar0][ac0] = *(const short8*)(A + (size_t)(row0 + ar0) * K + k0 + ac0);
    *(short8*)&As[ar1][ac1] = *(const short8*)(A + (size_t)(row0 + ar1) * K + k0 + ac1);
    *(short8*)&Bs[ar0][ac0] = *(const short8*)(Bt + (size_t)(col0 + ar0) * K + k0 + ac0);
    *(short8*)&Bs[ar1][ac1] = *(const short8*)(Bt + (size_t)(col0 + ar1) * K + k0 + ac1);
    __syncthreads();
#pragma unroll
    for (int ks = 0; ks < 64; ks += 32) {
      int kf = ks + quad * 8;
      short8 a0 = *(const short8*)&As[wr + l16][kf];
      short8 a1 = *(const short8*)&As[wr + 16 + l16][kf];
      short8 b0 = *(const short8*)&Bs[wc + l16][kf];
      short8 b1 = *(const short8*)&Bs[wc + 16 + l16][kf];
      acc[0][0] = __builtin_amdgcn_mfma_f32_16x16x32_bf16(a0, b0, acc[0][0], 0, 0, 0);
      acc[0][1] = __builtin_amdgcn_mfma_f32_16x16x32_bf16(a0, b1, acc[0][1], 0, 0, 0);
      acc[1][0] = __builtin_amdgcn_mfma_f32_16x16x32_bf16(a1, b0, acc[1][0], 0, 0, 0);
      acc[1][1] = __builtin_amdgcn_mfma_f32_16x16x32_bf16(a1, b1, acc[1][1], 0, 0, 0);
    }
    __syncthreads();
  }

#pragma unroll
  for (int ti = 0; ti < 2; ti++)
#pragma unroll
    for (int tj = 0; tj < 2; tj++) {
      int rbase = row0 + wr + ti * 16 + quad * 4;
      int c = col0 + wc + tj * 16 + l16;
      float bv = bias[c];
#pragma unroll
      for (int r = 0; r < 4; r++) {
        float v = acc[ti][tj][r] + bv;
        size_t idx = (size_t)(rbase + r) * N + c;
        if (mode == 0) {
          ((float*)Cout)[idx] = v;
        } else {
          float g = 0.5f * v * (1.f + erff(v * 0.70710678118f));
          ((u16*)Cout)[idx] = f2bf(g);
        }
      }
    }
}

// ---------------------------------------------------------------------------
// qkv reshape: qkvbuf f32 [B*S][3072] (col = h*192 + part*64 + d) ->
//   Q  bf16 [bh][s][64]      (natural)
//   K  bf16 [bh][s][64]      (natural)
//   VT bf16 [bh][64][s]      (transposed)
// One block per (s-tile 64, h, b).
// ---------------------------------------------------------------------------
__global__ __launch_bounds__(256) void qkv_reshape(
    const float* __restrict__ qkv, u16* __restrict__ Q, u16* __restrict__ K,
    u16* __restrict__ VT)
{
  __shared__ float tile[64][65];
  int st = blockIdx.x, h = blockIdx.y, b = blockIdx.z;
  int bh = b * 16 + h;
  int t = threadIdx.x;
  int row = t >> 2, c0 = (t & 3) * 16;
  const float* src = qkv + (size_t)(b * 1024 + st * 64 + row) * 3072 + h * 192;

#pragma unroll
  for (int part = 0; part < 2; part++) {
    u16* dst = (part == 0 ? Q : K) + ((size_t)bh * 1024 + st * 64 + row) * 64 + c0;
#pragma unroll
    for (int i = 0; i < 4; i++) {
      float4 v = *(const float4*)(src + part * 64 + c0 + i * 4);
      ushort4 o; o.x = f2bf(v.x); o.y = f2bf(v.y); o.z = f2bf(v.z); o.w = f2bf(v.w);
      *(ushort4*)(dst + i * 4) = o;
    }
  }
  // V -> LDS (f32), then transposed bf16 out
#pragma unroll
  for (int i = 0; i < 4; i++) {
    float4 v = *(const float4*)(src + 128 + c0 + i * 4);
    tile[row][c0 + i * 4 + 0] = v.x;
    tile[row][c0 + i * 4 + 1] = v.y;
    tile[row][c0 + i * 4 + 2] = v.z;
    tile[row][c0 + i * 4 + 3] = v.w;
  }
  __syncthreads();
  u16* dst = VT + ((size_t)bh * 64 + row) * 1024 + st * 64 + c0;
#pragma unroll
  for (int i = 0; i < 4; i++) {
    ushort4 o;
    o.x = f2bf(tile[c0 + i * 4 + 0][row]);
    o.y = f2bf(tile[c0 + i * 4 + 1][row]);
    o.z = f2bf(tile[c0 + i * 4 + 2][row]);
    o.w = f2bf(tile[c0 + i * 4 + 3][row]);
    *(ushort4*)(dst + i * 4) = o;
  }
}

// ---------------------------------------------------------------------------
// Flash attention: one block per (q-tile 64, h, b). 4 waves x 16 q-rows.
// MFMA QK^T and PV with online softmax; K and V^T fragments read directly
// from global (L2-resident); P round-trips through LDS for layout change.
// Output bf16 [b*S + s][h*64 + d].
// ---------------------------------------------------------------------------
__global__ __launch_bounds__(256) void flash_attn(
    const u16* __restrict__ Q, const u16* __restrict__ K,
    const u16* __restrict__ VT, u16* __restrict__ out)
{
  __shared__ alignas(16) u16 Ps[64][72];
  int qt = (int)gridDim.x - 1 - (int)blockIdx.x;  // big tiles first
  int h = blockIdx.y, b = blockIdx.z;
  int bh = b * 16 + h;
  int t = threadIdx.x;
  int wv = t >> 6, lane = t & 63, l16 = lane & 15, quad = lane >> 4;
  int qrow0 = qt * 64 + wv * 16;

  const u16* Qb = Q + (size_t)bh * 1024 * 64;
  const u16* Kb = K + (size_t)bh * 1024 * 64;
  const u16* Vb = VT + (size_t)bh * 64 * 1024;

  short8 qfrag[2];
  qfrag[0] = *(const short8*)(Qb + (size_t)(qrow0 + l16) * 64 + quad * 8);
  qfrag[1] = *(const short8*)(Qb + (size_t)(qrow0 + l16) * 64 + 32 + quad * 8);

  floatx4 accO[4];
#pragma unroll
  for (int i = 0; i < 4; i++) accO[i] = (floatx4){0.f, 0.f, 0.f, 0.f};
  float m[4], l[4];
#pragma unroll
  for (int r = 0; r < 4; r++) { m[r] = -3.0e38f; l[r] = 0.f; }

  for (int jt = 0; jt <= qt; jt++) {
    const u16* Kt = Kb + (size_t)(jt * 64) * 64;
    float sv[4][4];
    bool diag = (jt == qt);
#pragma unroll
    for (int nt = 0; nt < 4; nt++) {
      short8 b0 = *(const short8*)(Kt + (size_t)(nt * 16 + l16) * 64 + quad * 8);
      short8 b1 = *(const short8*)(Kt + (size_t)(nt * 16 + l16) * 64 + 32 + quad * 8);
      floatx4 acc = (floatx4){0.f, 0.f, 0.f, 0.f};
      acc = __builtin_amdgcn_mfma_f32_16x16x32_bf16(qfrag[0], b0, acc, 0, 0, 0);
      acc = __builtin_amdgcn_mfma_f32_16x16x32_bf16(qfrag[1], b1, acc, 0, 0, 0);
#pragma unroll
      for (int r = 0; r < 4; r++) {
        float v = acc[r] * 0.125f;
        if (diag) {
          int j = nt * 16 + l16;
          int q = wv * 16 + quad * 4 + r;
          if (j > q) v = -3.0e38f;
        }
        sv[nt][r] = v;
      }
    }
    // row max over the 64-wide tile
    float rm[4];
#pragma unroll
    for (int r = 0; r < 4; r++) {
      rm[r] = fmaxf(fmaxf(sv[0][r], sv[1][r]), fmaxf(sv[2][r], sv[3][r]));
#pragma unroll
      for (int off = 1; off < 16; off <<= 1)
        rm[r] = fmaxf(rm[r], __shfl_xor(rm[r], off, 64));
    }
    float al[4], rs[4];
    float p[4][4];
#pragma unroll
    for (int r = 0; r < 4; r++) {
      float mn = fmaxf(m[r], rm[r]);
      al[r] = __expf(m[r] - mn);
      m[r] = mn;
      rs[r] = 0.f;
    }
#pragma unroll
    for (int nt = 0; nt < 4; nt++)
#pragma unroll
      for (int r = 0; r < 4; r++) {
        float e = __expf(sv[nt][r] - m[r]);
        p[nt][r] = e;
        rs[r] += e;
      }
#pragma unroll
    for (int r = 0; r < 4; r++) {
#pragma unroll
      for (int off = 1; off < 16; off <<= 1)
        rs[r] += __shfl_xor(rs[r], off, 64);
      l[r] = l[r] * al[r] + rs[r];
    }
#pragma unroll
    for (int nt = 0; nt < 4; nt++)
#pragma unroll
      for (int r = 0; r < 4; r++) accO[nt][r] *= al[r];

    __syncthreads();  // protect Ps against previous iteration's readers
#pragma unroll
    for (int nt = 0; nt < 4; nt++)
#pragma unroll
      for (int r = 0; r < 4; r++)
        Ps[wv * 16 + quad * 4 + r][nt * 16 + l16] = f2bf(p[nt][r]);
    __syncthreads();

    short8 pf0 = *(const short8*)&Ps[wv * 16 + l16][quad * 8];
    short8 pf1 = *(const short8*)&Ps[wv * 16 + l16][32 + quad * 8];
#pragma unroll
    for (int nt = 0; nt < 4; nt++) {
      const u16* Vt = Vb + (size_t)(nt * 16 + l16) * 1024 + jt * 64;
      short8 v0 = *(const short8*)(Vt + quad * 8);
      short8 v1 = *(const short8*)(Vt + 32 + quad * 8);
      accO[nt] = __builtin_amdgcn_mfma_f32_16x16x32_bf16(pf0, v0, accO[nt], 0, 0, 0);
      accO[nt] = __builtin_amdgcn_mfma_f32_16x16x32_bf16(pf1, v1, accO[nt], 0, 0, 0);
    }
  }

  // epilogue: normalize, coalesce through LDS, store
  float inv[4];
#pragma unroll
  for (int r = 0; r < 4; r++) inv[r] = 1.f / l[r];
  __syncthreads();
#pragma unroll
  for (int nt = 0; nt < 4; nt++)
#pragma unroll
    for (int r = 0; r < 4; r++)
      Ps[wv * 16 + quad * 4 + r][nt * 16 + l16] = f2bf(accO[nt][r] * inv[r]);
  __syncthreads();
  int r = t >> 2, c0 = (t & 3) * 16;
  short8 o0 = *(const short8*)&Ps[r][c0];
  short8 o1 = *(const short8*)&Ps[r][c0 + 8];
  u16* dst = out + (size_t)(b * 1024 + qt * 64 + r) * 1024 + h * 64 + c0;
  *(short8*)dst = o0;
  *(short8*)(dst + 8) = o1;
}

// ---------------------------------------------------------------------------
// LayerNorm( xin + add ) * sc + bi  -> xout (f32) and xbf (bf16).
// ---------------------------------------------------------------------------
__global__ __launch_bounds__(256) void ln_kernel(
    const float* __restrict__ xin, const float* __restrict__ add,
    const float* __restrict__ sc, const float* __restrict__ bi,
    float* __restrict__ xout, u16* __restrict__ xbf)
{
  int row = blockIdx.x, t = threadIdx.x;
  float4 v = *(const float4*)(xin + (size_t)row * 1024 + t * 4);
  if (add) {
    float4 a = *(const float4*)(add + (size_t)row * 1024 + t * 4);
    v.x += a.x; v.y += a.y; v.z += a.z; v.w += a.w;
  }
  float s1 = v.x + v.y + v.z + v.w;
  float s2 = v.x * v.x + v.y * v.y + v.z * v.z + v.w * v.w;
#pragma unroll
  for (int off = 32; off > 0; off >>= 1) {
    s1 += __shfl_down(s1, off);
    s2 += __shfl_down(s2, off);
  }
  __shared__ float r1[4], r2[4];
  int lane = t & 63, wv = t >> 6;
  if (lane == 0) { r1[wv] = s1; r2[wv] = s2; }
  __syncthreads();
  float S1 = r1[0] + r1[1] + r1[2] + r1[3];
  float S2 = r2[0] + r2[1] + r2[2] + r2[3];
  float mn = S1 * (1.f / 1024.f);
  float var = S2 * (1.f / 1024.f) - mn * mn;
  float inv = rsqrtf(var + 1e-5f);
  float4 sv = *(const float4*)(sc + t * 4);
  float4 bv = *(const float4*)(bi + t * 4);
  float4 o;
  o.x = (v.x - mn) * inv * sv.x + bv.x;
  o.y = (v.y - mn) * inv * sv.y + bv.y;
  o.z = (v.z - mn) * inv * sv.z + bv.z;
  o.w = (v.w - mn) * inv * sv.w + bv.w;
  *(float4*)(xout + (size_t)row * 1024 + t * 4) = o;
  ushort4 ob; ob.x = f2bf(o.x); ob.y = f2bf(o.y); ob.z = f2bf(o.z); ob.w = f2bf(o.w);
  *(ushort4*)(xbf + (size_t)row * 1024 + t * 4) = ob;
}

// ---------------------------------------------------------------------------
// In-place row softmax over V=32000.
// ---------------------------------------------------------------------------
__global__ __launch_bounds__(256) void softmax_kernel(float* __restrict__ out)
{
  __shared__ float red[256];
  int row = blockIdx.x, t = threadIdx.x;
  float* p = out + (size_t)row * 32000;
  float lmax = -1e30f;
  for (int j = t; j < 32000; j += 256) lmax = fmaxf(lmax, p[j]);
  red[t] = lmax; __syncthreads();
  for (int off = 128; off > 0; off >>= 1) {
    if (t < off) red[t] = fmaxf(red[t], red[t + off]);
    __syncthreads();
  }
  float mx = red[0];
  __syncthreads();
  float lsum = 0.f;
  for (int j = t; j < 32000; j += 256) {
    float e = __expf(p[j] - mx);
    p[j] = e;
    lsum += e;
  }
  red[t] = lsum; __syncthreads();
  for (int off = 128; off > 0; off >>= 1) {
    if (t < off) red[t] += red[t + off];
    __syncthreads();
  }
  float inv = 1.f / red[0];
  for (int j = t; j < 32000; j += 256) p[j] *= inv;
}

// ---------------------------------------------------------------------------
// Launch
// ---------------------------------------------------------------------------
extern "C" void kernel_launch(void* const* d_in, const int* in_sizes, int n_in,
                              void* d_out, int out_size, void* d_ws, size_t ws_size,
                              hipStream_t stream)
{
  const int*   X       = (const int*)d_in[0];
  const float* tok_emb = (const float*)d_in[1];
  const float* pos_emb = (const float*)d_in[2];
  const float* qkv_w   = (const float*)d_in[3];
  const float* qkv_b   = (const float*)d_in[4];
  const float* out_w   = (const float*)d_in[5];
  const float* out_b   = (const float*)d_in[6];
  const float* ln1_s   = (const float*)d_in[7];
  const float* ln1_b   = (const float*)d_in[8];
  const float* ln2_s   = (const float*)d_in[9];
  const float* ln2_b   = (const float*)d_in[10];
  const float* ff1_w   = (const float*)d_in[11];
  const float* ff1_b   = (const float*)d_in[12];
  const float* ff2_w   = (const float*)d_in[13];
  const float* ff2_b   = (const float*)d_in[14];
  const float* lnf_s   = (const float*)d_in[15];
  const float* lnf_b   = (const float*)d_in[16];
  const float* head_w  = (const float*)d_in[17];
  const float* head_b  = (const float*)d_in[18];

  char* ws = (char*)d_ws;
  float* x      = (float*)ws;            ws += 2048ull * 1024 * 4;
  u16*   xbf    = (u16*)ws;              ws += 2048ull * 1024 * 2;
  float* qkvbuf = (float*)ws;            ws += 2048ull * 3072 * 4;
  u16*   attnbf = (u16*)ws;              ws += 2048ull * 1024 * 2;
  float* tmp    = (float*)ws;            ws += 2048ull * 1024 * 4;
  u16*   hbf    = (u16*)ws;              ws += 2048ull * 4096 * 2;
  u16*   qkvT   = (u16*)ws;              ws += 3072ull * 1024 * 2;
  u16*   outT   = (u16*)ws;              ws += 1024ull * 1024 * 2;
  u16*   ff1T   = (u16*)ws;              ws += 4096ull * 1024 * 2;
  u16*   ff2T   = (u16*)ws;              ws += 1024ull * 4096 * 2;
  u16*   headT  = (u16*)ws;              ws += 32000ull * 1024 * 2;

  // Q/K/VT carved out of hbf (hbf only live during the FF phase; these only
  // live during attention — no overlap within a layer, identical every call).
  u16* Qbf = hbf;
  u16* Kbf = hbf + 2048ull * 1024;
  u16* VTb = hbf + 2 * 2048ull * 1024;

  dim3 tb(32, 8);
  transpose_bf16<<<dim3(3072 / 32, 1024 / 32), tb, 0, stream>>>(qkv_w, qkvT, 1024, 3072);
  transpose_bf16<<<dim3(1024 / 32, 1024 / 32), tb, 0, stream>>>(out_w, outT, 1024, 1024);
  transpose_bf16<<<dim3(4096 / 32, 1024 / 32), tb, 0, stream>>>(ff1_w, ff1T, 1024, 4096);
  transpose_bf16<<<dim3(1024 / 32, 4096 / 32), tb, 0, stream>>>(ff2_w, ff2T, 4096, 1024);
  transpose_bf16<<<dim3(32000 / 32, 1024 / 32), tb, 0, stream>>>(head_w, headT, 1024, 32000);

  embed_kernel<<<2048, 256, 0, stream>>>(X, tok_emb, pos_emb, x, xbf);

  for (int l = 0; l < 6; l++) {
    gemm_bf16<<<dim3(3072 / 64, 2048 / 64), 256, 0, stream>>>(
        xbf, qkvT, qkv_b, qkvbuf, 2048, 3072, 1024, 0);
    qkv_reshape<<<dim3(16, 16, 2), 256, 0, stream>>>(qkvbuf, Qbf, Kbf, VTb);
    flash_attn<<<dim3(16, 16, 2), 256, 0, stream>>>(Qbf, Kbf, VTb, attnbf);
    gemm_bf16<<<dim3(1024 / 64, 2048 / 64), 256, 0, stream>>>(
        attnbf, outT, out_b, tmp, 2048, 1024, 1024, 0);
    ln_kernel<<<2048, 256, 0, stream>>>(x, tmp, ln1_s, ln1_b, x, xbf);
    gemm_bf16<<<dim3(4096 / 64, 2048 / 64), 256, 0, stream>>>(
        xbf, ff1T, ff1_b, hbf, 2048, 4096, 1024, 1);
    gemm_bf16<<<dim3(1024 / 64, 2048 / 64), 256, 0, stream>>>(
        hbf, ff2T, ff2_b, tmp, 2048, 1024, 4096, 0);
    ln_kernel<<<2048, 256, 0, stream>>>(x, tmp, ln2_s, ln2_b, x, xbf);
  }

  ln_kernel<<<2048, 256, 0, stream>>>(x, nullptr, lnf_s, lnf_b, x, xbf);
  gemm_bf16<<<dim3(32000 / 64, 2048 / 64), 256, 0, stream>>>(
      xbf, headT, head_b, (float*)d_out, 2048, 32000, 1024, 0);
  softmax_kernel<<<2048, 256, 0, stream>>>((float*)d_out);
}

// Round 3
// 2146.734 us; speedup vs baseline: 3.6386x; 1.2942x over previous
//
#include <hip/hip_runtime.h>
#include <math.h>

typedef unsigned short u16;
typedef short short8 __attribute__((ext_vector_type(8)));
typedef float floatx4 __attribute__((ext_vector_type(4)));

__device__ __forceinline__ u16 f2bf(float f) {
  unsigned int u = __float_as_uint(f);
  u += 0x7fffu + ((u >> 16) & 1u);
  return (u16)(u >> 16);
}

// async 16B global->LDS (DMA; LDS dest = wave-uniform base + lane*16)
__device__ __forceinline__ void gld_lds16(const void* g, void* l) {
  __builtin_amdgcn_global_load_lds(
      (__attribute__((address_space(1))) void*)(g),
      (__attribute__((address_space(3))) void*)(l), 16, 0, 0);
}

// ---------------------------------------------------------------------------
// Transpose + f32->bf16 convert: W[K][N] -> Wt[N][K]
// ---------------------------------------------------------------------------
__global__ __launch_bounds__(256) void transpose_bf16(
    const float* __restrict__ W, u16* __restrict__ Wt, int K, int N)
{
  __shared__ float tile[32][33];
  int tx = threadIdx.x, ty = threadIdx.y;
  int n0 = blockIdx.x * 32, k0 = blockIdx.y * 32;
#pragma unroll
  for (int i = 0; i < 4; i++) {
    int k = k0 + ty + i * 8;
    tile[ty + i * 8][tx] = W[(size_t)k * N + n0 + tx];
  }
  __syncthreads();
#pragma unroll
  for (int i = 0; i < 4; i++) {
    int n = n0 + ty + i * 8;
    Wt[(size_t)n * K + k0 + tx] = f2bf(tile[tx][ty + i * 8]);
  }
}

// ---------------------------------------------------------------------------
// Embedding
// ---------------------------------------------------------------------------
__global__ __launch_bounds__(256) void embed_kernel(
    const int* __restrict__ X, const float* __restrict__ tok,
    const float* __restrict__ pos, float* __restrict__ x, u16* __restrict__ xbf)
{
  int bs = blockIdx.x, t = threadIdx.x;
  int id = X[bs];
  int s = bs & 1023;
  float4 tv = *(const float4*)(tok + (size_t)id * 1024 + t * 4);
  float4 pv = *(const float4*)(pos + (size_t)s * 1024 + t * 4);
  float4 o;
  o.x = tv.x + pv.x; o.y = tv.y + pv.y; o.z = tv.z + pv.z; o.w = tv.w + pv.w;
  *(float4*)(x + (size_t)bs * 1024 + t * 4) = o;
  ushort4 ob; ob.x = f2bf(o.x); ob.y = f2bf(o.y); ob.z = f2bf(o.z); ob.w = f2bf(o.w);
  *(ushort4*)(xbf + (size_t)bs * 1024 + t * 4) = ob;
}

// ---------------------------------------------------------------------------
// MFMA GEMM, m97-style: C[M][N] = A[M][K] @ Bt[N][K]^T + bias
// BM x 128 tile, BK=64, global_load_lds width-16 staging with XOR column
// swizzle (kills the 16-way ds_read bank conflict at zero cost).
// Waves: 4 total, grid (4/WGC) x WGC; wave tile = WTR*16 x WTC*16.
// mode 0: C f32.  mode 1: C bf16 with exact GELU.
// ---------------------------------------------------------------------------
template<int BM, int WGC, int WTR, int WTC>
__global__ __launch_bounds__(256) void gemm_mfma(
    const u16* __restrict__ A, const u16* __restrict__ Bt,
    const float* __restrict__ bias, void* __restrict__ Cout,
    int M, int N, int K, int mode)
{
  constexpr int BN = WGC * WTC * 16;
  static_assert(BN == 128, "BN must be 128");
  __shared__ alignas(16) u16 As[BM * 64];
  __shared__ alignas(16) u16 Bs[128 * 64];

  const int t = threadIdx.x;
  const int wv = t >> 6, lane = t & 63;
  const int quad = lane >> 4, l16 = lane & 15;
  const int row0 = blockIdx.y * BM, col0 = blockIdx.x * BN;
  const int wr = (wv / WGC) * (WTR * 16);
  const int wc = (wv % WGC) * (WTC * 16);

  floatx4 acc[WTR][WTC];
#pragma unroll
  for (int i = 0; i < WTR; i++)
#pragma unroll
    for (int j = 0; j < WTC; j++) acc[i][j] = (floatx4){0.f, 0.f, 0.f, 0.f};

  // staging geometry: chunk = 8 rows x 64 cols (1 KB). lane -> (row, swizzled col)
  const int srow = lane >> 3;                 // row within chunk
  const int scol = ((lane & 7) ^ srow) * 8;   // XOR-swizzled column group
  const int swz = l16 & 7;                    // fragment-read swizzle key

  const u16* Abase = A + (size_t)row0 * K;
  const u16* Bbase = Bt + (size_t)col0 * K;
  constexpr int CA = BM / 32;  // A chunks per wave
  constexpr int CB = 4;        // B chunks per wave

  for (int k0 = 0; k0 < K; k0 += 64) {
#pragma unroll
    for (int i = 0; i < CA; i++) {
      int chunk = wv * CA + i;
      gld_lds16(Abase + (size_t)(chunk * 8 + srow) * K + k0 + scol, &As[chunk * 512]);
    }
#pragma unroll
    for (int i = 0; i < CB; i++) {
      int chunk = wv * CB + i;
      gld_lds16(Bbase + (size_t)(chunk * 8 + srow) * K + k0 + scol, &Bs[chunk * 512]);
    }
    __syncthreads();
#pragma unroll
    for (int ks = 0; ks < 64; ks += 32) {
      const int g = quad | (ks >> 3);          // global column group 0..7
      const int cofs = ((g ^ swz) * 8);        // swizzled LDS column
      short8 a[WTR], b[WTC];
#pragma unroll
      for (int i = 0; i < WTR; i++)
        a[i] = *(const short8*)&As[(wr + i * 16 + l16) * 64 + cofs];
#pragma unroll
      for (int j = 0; j < WTC; j++)
        b[j] = *(const short8*)&Bs[(wc + j * 16 + l16) * 64 + cofs];
#pragma unroll
      for (int i = 0; i < WTR; i++)
#pragma unroll
        for (int j = 0; j < WTC; j++)
          acc[i][j] = __builtin_amdgcn_mfma_f32_16x16x32_bf16(a[i], b[j], acc[i][j], 0, 0, 0);
    }
    __syncthreads();
  }

#pragma unroll
  for (int i = 0; i < WTR; i++) {
    int rbase = row0 + wr + i * 16 + quad * 4;
#pragma unroll
    for (int j = 0; j < WTC; j++) {
      int c = col0 + wc + j * 16 + l16;
      float bv = bias[c];
#pragma unroll
      for (int r = 0; r < 4; r++) {
        float v = acc[i][j][r] + bv;
        size_t idx = (size_t)(rbase + r) * N + c;
        if (mode == 0) {
          ((float*)Cout)[idx] = v;
        } else {
          float gl = 0.5f * v * (1.f + erff(v * 0.70710678118f));
          ((u16*)Cout)[idx] = f2bf(gl);
        }
      }
    }
  }
}

// ---------------------------------------------------------------------------
// qkv reshape -> Q [bh][s][64], K [bh][s][64], VT [bh][64][s] (bf16)
// ---------------------------------------------------------------------------
__global__ __launch_bounds__(256) void qkv_reshape(
    const float* __restrict__ qkv, u16* __restrict__ Q, u16* __restrict__ K,
    u16* __restrict__ VT)
{
  __shared__ float tile[64][65];
  int st = blockIdx.x, h = blockIdx.y, b = blockIdx.z;
  int bh = b * 16 + h;
  int t = threadIdx.x;
  int row = t >> 2, c0 = (t & 3) * 16;
  const float* src = qkv + (size_t)(b * 1024 + st * 64 + row) * 3072 + h * 192;

#pragma unroll
  for (int part = 0; part < 2; part++) {
    u16* dst = (part == 0 ? Q : K) + ((size_t)bh * 1024 + st * 64 + row) * 64 + c0;
#pragma unroll
    for (int i = 0; i < 4; i++) {
      float4 v = *(const float4*)(src + part * 64 + c0 + i * 4);
      ushort4 o; o.x = f2bf(v.x); o.y = f2bf(v.y); o.z = f2bf(v.z); o.w = f2bf(v.w);
      *(ushort4*)(dst + i * 4) = o;
    }
  }
#pragma unroll
  for (int i = 0; i < 4; i++) {
    float4 v = *(const float4*)(src + 128 + c0 + i * 4);
    tile[row][c0 + i * 4 + 0] = v.x;
    tile[row][c0 + i * 4 + 1] = v.y;
    tile[row][c0 + i * 4 + 2] = v.z;
    tile[row][c0 + i * 4 + 3] = v.w;
  }
  __syncthreads();
  u16* dst = VT + ((size_t)bh * 64 + row) * 1024 + st * 64 + c0;
#pragma unroll
  for (int i = 0; i < 4; i++) {
    ushort4 o;
    o.x = f2bf(tile[c0 + i * 4 + 0][row]);
    o.y = f2bf(tile[c0 + i * 4 + 1][row]);
    o.z = f2bf(tile[c0 + i * 4 + 2][row]);
    o.w = f2bf(tile[c0 + i * 4 + 3][row]);
    *(ushort4*)(dst + i * 4) = o;
  }
}

// ---------------------------------------------------------------------------
// Flash attention (unchanged from round 2 — not a bottleneck)
// ---------------------------------------------------------------------------
__global__ __launch_bounds__(256) void flash_attn(
    const u16* __restrict__ Q, const u16* __restrict__ K,
    const u16* __restrict__ VT, u16* __restrict__ out)
{
  __shared__ alignas(16) u16 Ps[64][72];
  int qt = (int)gridDim.x - 1 - (int)blockIdx.x;
  int h = blockIdx.y, b = blockIdx.z;
  int bh = b * 16 + h;
  int t = threadIdx.x;
  int wv = t >> 6, lane = t & 63, l16 = lane & 15, quad = lane >> 4;
  int qrow0 = qt * 64 + wv * 16;

  const u16* Qb = Q + (size_t)bh * 1024 * 64;
  const u16* Kb = K + (size_t)bh * 1024 * 64;
  const u16* Vb = VT + (size_t)bh * 64 * 1024;

  short8 qfrag[2];
  qfrag[0] = *(const short8*)(Qb + (size_t)(qrow0 + l16) * 64 + quad * 8);
  qfrag[1] = *(const short8*)(Qb + (size_t)(qrow0 + l16) * 64 + 32 + quad * 8);

  floatx4 accO[4];
#pragma unroll
  for (int i = 0; i < 4; i++) accO[i] = (floatx4){0.f, 0.f, 0.f, 0.f};
  float m[4], l[4];
#pragma unroll
  for (int r = 0; r < 4; r++) { m[r] = -3.0e38f; l[r] = 0.f; }

  for (int jt = 0; jt <= qt; jt++) {
    const u16* Kt = Kb + (size_t)(jt * 64) * 64;
    float sv[4][4];
    bool diag = (jt == qt);
#pragma unroll
    for (int nt = 0; nt < 4; nt++) {
      short8 b0 = *(const short8*)(Kt + (size_t)(nt * 16 + l16) * 64 + quad * 8);
      short8 b1 = *(const short8*)(Kt + (size_t)(nt * 16 + l16) * 64 + 32 + quad * 8);
      floatx4 acc = (floatx4){0.f, 0.f, 0.f, 0.f};
      acc = __builtin_amdgcn_mfma_f32_16x16x32_bf16(qfrag[0], b0, acc, 0, 0, 0);
      acc = __builtin_amdgcn_mfma_f32_16x16x32_bf16(qfrag[1], b1, acc, 0, 0, 0);
#pragma unroll
      for (int r = 0; r < 4; r++) {
        float v = acc[r] * 0.125f;
        if (diag) {
          int j = nt * 16 + l16;
          int q = wv * 16 + quad * 4 + r;
          if (j > q) v = -3.0e38f;
        }
        sv[nt][r] = v;
      }
    }
    float rm[4];
#pragma unroll
    for (int r = 0; r < 4; r++) {
      rm[r] = fmaxf(fmaxf(sv[0][r], sv[1][r]), fmaxf(sv[2][r], sv[3][r]));
#pragma unroll
      for (int off = 1; off < 16; off <<= 1)
        rm[r] = fmaxf(rm[r], __shfl_xor(rm[r], off, 64));
    }
    float al[4], rs[4];
    float p[4][4];
#pragma unroll
    for (int r = 0; r < 4; r++) {
      float mn = fmaxf(m[r], rm[r]);
      al[r] = __expf(m[r] - mn);
      m[r] = mn;
      rs[r] = 0.f;
    }
#pragma unroll
    for (int nt = 0; nt < 4; nt++)
#pragma unroll
      for (int r = 0; r < 4; r++) {
        float e = __expf(sv[nt][r] - m[r]);
        p[nt][r] = e;
        rs[r] += e;
      }
#pragma unroll
    for (int r = 0; r < 4; r++) {
#pragma unroll
      for (int off = 1; off < 16; off <<= 1)
        rs[r] += __shfl_xor(rs[r], off, 64);
      l[r] = l[r] * al[r] + rs[r];
    }
#pragma unroll
    for (int nt = 0; nt < 4; nt++)
#pragma unroll
      for (int r = 0; r < 4; r++) accO[nt][r] *= al[r];

    __syncthreads();
#pragma unroll
    for (int nt = 0; nt < 4; nt++)
#pragma unroll
      for (int r = 0; r < 4; r++)
        Ps[wv * 16 + quad * 4 + r][nt * 16 + l16] = f2bf(p[nt][r]);
    __syncthreads();

    short8 pf0 = *(const short8*)&Ps[wv * 16 + l16][quad * 8];
    short8 pf1 = *(const short8*)&Ps[wv * 16 + l16][32 + quad * 8];
#pragma unroll
    for (int nt = 0; nt < 4; nt++) {
      const u16* Vt = Vb + (size_t)(nt * 16 + l16) * 1024 + jt * 64;
      short8 v0 = *(const short8*)(Vt + quad * 8);
      short8 v1 = *(const short8*)(Vt + 32 + quad * 8);
      accO[nt] = __builtin_amdgcn_mfma_f32_16x16x32_bf16(pf0, v0, accO[nt], 0, 0, 0);
      accO[nt] = __builtin_amdgcn_mfma_f32_16x16x32_bf16(pf1, v1, accO[nt], 0, 0, 0);
    }
  }

  float inv[4];
#pragma unroll
  for (int r = 0; r < 4; r++) inv[r] = 1.f / l[r];
  __syncthreads();
#pragma unroll
  for (int nt = 0; nt < 4; nt++)
#pragma unroll
    for (int r = 0; r < 4; r++)
      Ps[wv * 16 + quad * 4 + r][nt * 16 + l16] = f2bf(accO[nt][r] * inv[r]);
  __syncthreads();
  int r = t >> 2, c0 = (t & 3) * 16;
  short8 o0 = *(const short8*)&Ps[r][c0];
  short8 o1 = *(const short8*)&Ps[r][c0 + 8];
  u16* dst = out + (size_t)(b * 1024 + qt * 64 + r) * 1024 + h * 64 + c0;
  *(short8*)dst = o0;
  *(short8*)(dst + 8) = o1;
}

// ---------------------------------------------------------------------------
// LayerNorm( xin + add ) * sc + bi  -> xout (f32) and xbf (bf16).
// ---------------------------------------------------------------------------
__global__ __launch_bounds__(256) void ln_kernel(
    const float* __restrict__ xin, const float* __restrict__ add,
    const float* __restrict__ sc, const float* __restrict__ bi,
    float* __restrict__ xout, u16* __restrict__ xbf)
{
  int row = blockIdx.x, t = threadIdx.x;
  float4 v = *(const float4*)(xin + (size_t)row * 1024 + t * 4);
  if (add) {
    float4 a = *(const float4*)(add + (size_t)row * 1024 + t * 4);
    v.x += a.x; v.y += a.y; v.z += a.z; v.w += a.w;
  }
  float s1 = v.x + v.y + v.z + v.w;
  float s2 = v.x * v.x + v.y * v.y + v.z * v.z + v.w * v.w;
#pragma unroll
  for (int off = 32; off > 0; off >>= 1) {
    s1 += __shfl_down(s1, off);
    s2 += __shfl_down(s2, off);
  }
  __shared__ float r1[4], r2[4];
  int lane = t & 63, wv = t >> 6;
  if (lane == 0) { r1[wv] = s1; r2[wv] = s2; }
  __syncthreads();
  float S1 = r1[0] + r1[1] + r1[2] + r1[3];
  float S2 = r2[0] + r2[1] + r2[2] + r2[3];
  float mn = S1 * (1.f / 1024.f);
  float var = S2 * (1.f / 1024.f) - mn * mn;
  float inv = rsqrtf(var + 1e-5f);
  float4 sv = *(const float4*)(sc + t * 4);
  float4 bv = *(const float4*)(bi + t * 4);
  float4 o;
  o.x = (v.x - mn) * inv * sv.x + bv.x;
  o.y = (v.y - mn) * inv * sv.y + bv.y;
  o.z = (v.z - mn) * inv * sv.z + bv.z;
  o.w = (v.w - mn) * inv * sv.w + bv.w;
  *(float4*)(xout + (size_t)row * 1024 + t * 4) = o;
  ushort4 ob; ob.x = f2bf(o.x); ob.y = f2bf(o.y); ob.z = f2bf(o.z); ob.w = f2bf(o.w);
  *(ushort4*)(xbf + (size_t)row * 1024 + t * 4) = ob;
}

// ---------------------------------------------------------------------------
// Two-pass online softmax over V=32000 (1 read for max+sum, 1 read+write).
// ---------------------------------------------------------------------------
__global__ __launch_bounds__(256) void softmax_kernel(float* __restrict__ out)
{
  int row = blockIdx.x, t = threadIdx.x;
  float4* p4 = (float4*)(out + (size_t)row * 32000);
  float m = -3.0e38f, s = 0.f;
  for (int j = t; j < 8000; j += 256) {
    float4 v = p4[j];
    float vm = fmaxf(fmaxf(v.x, v.y), fmaxf(v.z, v.w));
    float mn = fmaxf(m, vm);
    s = s * __expf(m - mn) + __expf(v.x - mn) + __expf(v.y - mn) +
        __expf(v.z - mn) + __expf(v.w - mn);
    m = mn;
  }
  // wave reduce (m,s)
#pragma unroll
  for (int off = 32; off > 0; off >>= 1) {
    float m2 = __shfl_down(m, off), s2 = __shfl_down(s, off);
    float mn = fmaxf(m, m2);
    s = s * __expf(m - mn) + s2 * __expf(m2 - mn);
    m = mn;
  }
  __shared__ float rm[4], rs[4];
  int lane = t & 63, wv = t >> 6;
  if (lane == 0) { rm[wv] = m; rs[wv] = s; }
  __syncthreads();
  float M = rm[0], S = rs[0];
#pragma unroll
  for (int i = 1; i < 4; i++) {
    float mn = fmaxf(M, rm[i]);
    S = S * __expf(M - mn) + rs[i] * __expf(rm[i] - mn);
    M = mn;
  }
  float inv = 1.f / S;
  for (int j = t; j < 8000; j += 256) {
    float4 v = p4[j];
    v.x = __expf(v.x - M) * inv;
    v.y = __expf(v.y - M) * inv;
    v.z = __expf(v.z - M) * inv;
    v.w = __expf(v.w - M) * inv;
    p4[j] = v;
  }
}

// ---------------------------------------------------------------------------
// Launch
// ---------------------------------------------------------------------------
extern "C" void kernel_launch(void* const* d_in, const int* in_sizes, int n_in,
                              void* d_out, int out_size, void* d_ws, size_t ws_size,
                              hipStream_t stream)
{
  const int*   X       = (const int*)d_in[0];
  const float* tok_emb = (const float*)d_in[1];
  const float* pos_emb = (const float*)d_in[2];
  const float* qkv_w   = (const float*)d_in[3];
  const float* qkv_b   = (const float*)d_in[4];
  const float* out_w   = (const float*)d_in[5];
  const float* out_b   = (const float*)d_in[6];
  const float* ln1_s   = (const float*)d_in[7];
  const float* ln1_b   = (const float*)d_in[8];
  const float* ln2_s   = (const float*)d_in[9];
  const float* ln2_b   = (const float*)d_in[10];
  const float* ff1_w   = (const float*)d_in[11];
  const float* ff1_b   = (const float*)d_in[12];
  const float* ff2_w   = (const float*)d_in[13];
  const float* ff2_b   = (const float*)d_in[14];
  const float* lnf_s   = (const float*)d_in[15];
  const float* lnf_b   = (const float*)d_in[16];
  const float* head_w  = (const float*)d_in[17];
  const float* head_b  = (const float*)d_in[18];

  char* ws = (char*)d_ws;
  float* x      = (float*)ws;            ws += 2048ull * 1024 * 4;
  u16*   xbf    = (u16*)ws;              ws += 2048ull * 1024 * 2;
  float* qkvbuf = (float*)ws;            ws += 2048ull * 3072 * 4;
  u16*   attnbf = (u16*)ws;              ws += 2048ull * 1024 * 2;
  float* tmp    = (float*)ws;            ws += 2048ull * 1024 * 4;
  u16*   hbf    = (u16*)ws;              ws += 2048ull * 4096 * 2;
  u16*   qkvT   = (u16*)ws;              ws += 3072ull * 1024 * 2;
  u16*   outT   = (u16*)ws;              ws += 1024ull * 1024 * 2;
  u16*   ff1T   = (u16*)ws;              ws += 4096ull * 1024 * 2;
  u16*   ff2T   = (u16*)ws;              ws += 1024ull * 4096 * 2;
  u16*   headT  = (u16*)ws;              ws += 32000ull * 1024 * 2;

  u16* Qbf = hbf;
  u16* Kbf = hbf + 2048ull * 1024;
  u16* VTb = hbf + 2 * 2048ull * 1024;

  dim3 tb(32, 8);
  transpose_bf16<<<dim3(3072 / 32, 1024 / 32), tb, 0, stream>>>(qkv_w, qkvT, 1024, 3072);
  transpose_bf16<<<dim3(1024 / 32, 1024 / 32), tb, 0, stream>>>(out_w, outT, 1024, 1024);
  transpose_bf16<<<dim3(4096 / 32, 1024 / 32), tb, 0, stream>>>(ff1_w, ff1T, 1024, 4096);
  transpose_bf16<<<dim3(1024 / 32, 4096 / 32), tb, 0, stream>>>(ff2_w, ff2T, 4096, 1024);
  transpose_bf16<<<dim3(32000 / 32, 1024 / 32), tb, 0, stream>>>(head_w, headT, 1024, 32000);

  embed_kernel<<<2048, 256, 0, stream>>>(X, tok_emb, pos_emb, x, xbf);

  for (int l = 0; l < 6; l++) {
    gemm_mfma<128, 2, 4, 4><<<dim3(3072 / 128, 2048 / 128), 256, 0, stream>>>(
        xbf, qkvT, qkv_b, qkvbuf, 2048, 3072, 1024, 0);
    qkv_reshape<<<dim3(16, 16, 2), 256, 0, stream>>>(qkvbuf, Qbf, Kbf, VTb);
    flash_attn<<<dim3(16, 16, 2), 256, 0, stream>>>(Qbf, Kbf, VTb, attnbf);
    gemm_mfma<64, 4, 4, 2><<<dim3(1024 / 128, 2048 / 64), 256, 0, stream>>>(
        attnbf, outT, out_b, tmp, 2048, 1024, 1024, 0);
    ln_kernel<<<2048, 256, 0, stream>>>(x, tmp, ln1_s, ln1_b, x, xbf);
    gemm_mfma<128, 2, 4, 4><<<dim3(4096 / 128, 2048 / 128), 256, 0, stream>>>(
        xbf, ff1T, ff1_b, hbf, 2048, 4096, 1024, 1);
    gemm_mfma<64, 4, 4, 2><<<dim3(1024 / 128, 2048 / 64), 256, 0, stream>>>(
        hbf, ff2T, ff2_b, tmp, 2048, 1024, 4096, 0);
    ln_kernel<<<2048, 256, 0, stream>>>(x, tmp, ln2_s, ln2_b, x, xbf);
  }

  ln_kernel<<<2048, 256, 0, stream>>>(x, nullptr, lnf_s, lnf_b, x, xbf);
  gemm_mfma<128, 2, 4, 4><<<dim3(32000 / 128, 2048 / 128), 256, 0, stream>>>(
      xbf, headT, head_b, (float*)d_out, 2048, 32000, 1024, 0);
  softmax_kernel<<<2048, 256, 0, stream>>>((float*)d_out);
}